// Round 6
// baseline (12176.228 us; speedup 1.0000x reference)
//
#include <hip/hip_runtime.h>
#include <math.h>

#define FIN 1024
#define H 512
#define DD 256
#define NCLS 4
#define MAXC 64

// ws layout (bytes), runtime C:
//   counts int[MAXC] @ 0   (256 B)
//   flag   int       @ 256
//   sums   double[C*H]  @ 512
//   h_ws   double[C*H]  @ 512 + C*4096
//   ag_ws  double[C*DD] @ 512 + 2*C*4096
// total = 512 + C*10240

// ---------------- dtype detect: int32 vs int64 cluster_id ----------------
__global__ void detect_kernel(const int* __restrict__ cid32, int* flag, int n) {
    int i = blockIdx.x * blockDim.x + threadIdx.x;
    if (i < n && (i & 1) && cid32[i] != 0) atomicOr(flag, 1);
}

__device__ __forceinline__ int get_cid(const int* cid, int flag, int i) {
    return flag ? cid[i] : cid[2 * i];   // int32, or low word of int64
}

// ---------------- per-cluster row counts ----------------
__global__ void count_kernel(const int* __restrict__ cid, const int* __restrict__ flag,
                             int* counts, int n, int C) {
    int i = blockIdx.x * blockDim.x + threadIdx.x;
    if (i < n) {
        int c = get_cid(cid, *flag, i);
        if ((unsigned)c < (unsigned)C) atomicAdd(&counts[c], 1);
    }
}

// ------------- one block per row: 2-layer MLP + masked col-sum -------------
__global__ __launch_bounds__(256) void row_mlp(
    const float* __restrict__ x, const int* __restrict__ cid,
    const int* __restrict__ flag,
    const float* __restrict__ W1, const float* __restrict__ b1,
    const float* __restrict__ W2, const float* __restrict__ b2,
    double* __restrict__ sums, int n, int C)
{
    int r = blockIdx.x;
    if (r >= n) return;
    int c = get_cid(cid, *flag, r);
    if ((unsigned)c >= (unsigned)C) return;

    __shared__ float sx[FIN];   // 4 KB
    __shared__ float sh[H];     // 2 KB
    int tid = threadIdx.x;

    for (int i = tid; i < FIN; i += 256) sx[i] = x[(size_t)r * FIN + i];
    __syncthreads();

    const float* W1c = W1 + (size_t)c * FIN * H;
    const float* b1c = b1 + (size_t)c * H;
    for (int col = tid; col < H; col += 256) {
        float acc = 0.f;
        for (int k = 0; k < FIN; k++) acc += sx[k] * W1c[(size_t)k * H + col];
        acc += b1c[col];
        sh[col] = acc > 0.f ? acc : 0.f;
    }
    __syncthreads();

    const float* W2c = W2 + (size_t)c * H * H;
    const float* b2c = b2 + (size_t)c * H;
    for (int col = tid; col < H; col += 256) {
        float acc = 0.f;
        for (int k = 0; k < H; k++) acc += sh[k] * W2c[(size_t)k * H + col];
        acc += b2c[col];
        float y = acc > 0.f ? acc : 0.f;
        atomicAdd(&sums[(size_t)c * H + col], (double)y);
    }
}

// -------- tail1: h = relu(mean @ fcW + fcb), per (c, 128-col chunk) --------
__global__ __launch_bounds__(128) void tail1_kernel(
    const int* __restrict__ counts, const double* __restrict__ sums,
    const float* __restrict__ fcW, const float* __restrict__ fcb,
    double* __restrict__ h_ws)
{
    int b = blockIdx.x;
    int c = b >> 2, ch = b & 3;
    int tid = threadIdx.x;
    __shared__ double shc[H];
    double denom = fmax((double)counts[c], 1.0);
    for (int i = tid; i < H; i += 128) shc[i] = sums[(size_t)c * H + i] / denom;
    __syncthreads();
    int col = ch * 128 + tid;
    double acc = (double)fcb[col];
    for (int k = 0; k < H; k++) acc += shc[k] * (double)fcW[k * H + col];
    h_ws[(size_t)c * H + col] = acc > 0.0 ? acc : 0.0;
}

// -------- tail2a: ag = tanh(h@aW+ab) * sigmoid(h@gW+gb), per (c, chunk) ----
__global__ __launch_bounds__(128) void tail2a_kernel(
    const double* __restrict__ h_ws,
    const float* __restrict__ aW, const float* __restrict__ ab,
    const float* __restrict__ gW, const float* __restrict__ gb,
    double* __restrict__ ag_ws)
{
    int b = blockIdx.x;
    int c = b >> 1, dh = b & 1;
    int tid = threadIdx.x;
    __shared__ double sh[H];
    for (int i = tid; i < H; i += 128) sh[i] = h_ws[(size_t)c * H + i];
    __syncthreads();
    int d = dh * 128 + tid;
    double aa = (double)ab[d], gg = (double)gb[d];
    for (int k = 0; k < H; k++) {
        double hv = sh[k];
        aa += hv * (double)aW[k * DD + d];
        gg += hv * (double)gW[k * DD + d];
    }
    ag_ws[(size_t)c * DD + d] = tanh(aa) / (1.0 + exp(-gg));
}

// -------- tail2b: attention + rho + cls + outputs + diagnostics ------------
__global__ __launch_bounds__(256) void tail2b_kernel(
    const double* __restrict__ h_ws, const double* __restrict__ ag_ws,
    const float* __restrict__ cW, const float* __restrict__ cb,
    const float* __restrict__ rhoW, const float* __restrict__ rhob,
    const float* __restrict__ clsW, const float* __restrict__ clsb,
    const int* __restrict__ counts, const double* __restrict__ sums,
    const int* __restrict__ cid_raw, int n, int C,
    float* __restrict__ out)
{
    int tid = threadIdx.x;
    __shared__ double sA[MAXC];
    __shared__ double shp[H];
    __shared__ double sr[DD];

    if (tid < C) {
        double acc = (double)cb[0];
        for (int d = 0; d < DD; d++)
            acc += ag_ws[(size_t)tid * DD + d] * (double)cW[d];
        sA[tid] = acc;
    }
    __syncthreads();
    if (tid == 0) {
        double m = sA[0];
        for (int c = 1; c < C; c++) m = fmax(m, sA[c]);
        double s = 0.0;
        for (int c = 0; c < C; c++) { sA[c] = exp(sA[c] - m); s += sA[c]; }
        for (int c = 0; c < C; c++) sA[c] /= s;
    }
    __syncthreads();
    for (int col = tid; col < H; col += 256) {
        double s = 0.0;
        for (int c = 0; c < C; c++) s += sA[c] * h_ws[(size_t)c * H + col];
        shp[col] = s;
    }
    __syncthreads();
    for (int d = tid; d < DD; d += 256) {
        double acc = (double)rhob[d];
        for (int k = 0; k < H; k++) acc += shp[k] * (double)rhoW[k * DD + d];
        sr[d] = acc > 0.0 ? acc : 0.0;
    }
    __syncthreads();
    if (tid == 0) {
        double lg[NCLS];
        for (int kk = 0; kk < NCLS; kk++) {
            double acc = (double)clsb[kk];
            for (int d = 0; d < DD; d++) acc += sr[d] * (double)clsW[d * NCLS + kk];
            lg[kk] = acc;
        }
        int am = 0;
        double best = lg[0];
        double run = 1.0;
        for (int kk = 0; kk < NCLS; kk++) {
            if (lg[kk] > best) { best = lg[kk]; am = kk; }
            double hz = 1.0 / (1.0 + exp(-lg[kk]));
            out[kk] = (float)hz;            // hazards
            run *= (1.0 - hz);
            out[NCLS + kk] = (float)run;    // S
        }
        // ---- stage diagnostics (fire only in failure regimes) ----
        long long cnt_total = 0;
        for (int c = 0; c < C; c++) cnt_total += counts[c];
        double maxs = 0.0;
        for (int i = 0; i < C * H; i++) maxs = fmax(maxs, fabs(sums[i]));
        float yout;
        if (cnt_total == 0) {
            // decode dead: leak low-12 bits of first two raw words
            yout = 4.0e6f + (float)((cid_raw[0] & 0xFFF) + 4096 * (cid_raw[1] & 0xFFF));
        } else if (cnt_total != (long long)n) {
            yout = 2.0e6f + (float)cnt_total;   // partial decode
        } else if (maxs == 0.0) {
            yout = 3.0e6f;                      // counting OK, MLP dead
        } else {
            yout = (float)am;                   // healthy
        }
        out[2 * NCLS] = yout;
    }
}

// -------- host-side sentinel: shapes or ws insufficient --------
__global__ void diag_kernel(float* __restrict__ out, float code) {
    if (threadIdx.x == 0) {
        double run = 1.0;
        for (int kk = 0; kk < NCLS; kk++) {
            out[kk] = 0.5f;
            run *= 0.5;
            out[NCLS + kk] = (float)run;
        }
        out[2 * NCLS] = code;
    }
}

extern "C" void kernel_launch(void* const* d_in, const int* in_sizes, int n_in,
                              void* d_out, int out_size, void* d_ws, size_t ws_size,
                              hipStream_t stream) {
    const float* x    = (const float*)d_in[0];
    const int*   cid  = (const int*)d_in[1];
    const float* W1   = (const float*)d_in[2];
    const float* b1   = (const float*)d_in[3];
    const float* W2   = (const float*)d_in[4];
    const float* b2   = (const float*)d_in[5];
    const float* fcW  = (const float*)d_in[6];
    const float* fcb  = (const float*)d_in[7];
    const float* aW   = (const float*)d_in[8];
    const float* ab   = (const float*)d_in[9];
    const float* gW   = (const float*)d_in[10];
    const float* gb   = (const float*)d_in[11];
    const float* cW   = (const float*)d_in[12];
    const float* cb   = (const float*)d_in[13];
    const float* rhoW = (const float*)d_in[14];
    const float* rhob = (const float*)d_in[15];
    const float* clsW = (const float*)d_in[16];
    const float* clsb = (const float*)d_in[17];
    float* out = (float*)d_out;

    // ---- derive all shapes from in_sizes (hardcoding C burned 5 rounds) ----
    long long n  = in_sizes[1];                         // cluster_id count = N
    long long C  = (in_sizes[7] > 0) ? (long long)in_sizes[3] / in_sizes[7] : 0;
    bool shapes_ok =
        n > 0 &&
        (long long)in_sizes[0] == n * FIN &&            // x_path = N*1024
        in_sizes[7] == H &&                             // fc_b = (H,)
        in_sizes[9] == DD &&                            // a_b = (D,)
        in_sizes[17] == NCLS &&                         // cls_b = (NCLS,)
        C >= 1 && C <= MAXC &&
        (long long)in_sizes[2] == C * FIN * H &&        // W1 = (C,FIN,H)
        (long long)in_sizes[4] == C * H * H;            // W2 = (C,H,H)

    size_t sums_off = 512;
    size_t hws_off  = 512 + (size_t)C * H * 8;
    size_t agws_off = hws_off + (size_t)C * H * 8;
    size_t ws_need  = agws_off + (size_t)C * DD * 8;

    if (!shapes_ok) {
        diag_kernel<<<1, 64, 0, stream>>>(out, 7.0e6f + (float)(C >= 0 ? C : 0));
        return;
    }
    if (ws_size < ws_need) {
        diag_kernel<<<1, 64, 0, stream>>>(
            out, 6.0e6f + (float)(ws_size > 0 ? (ws_size >> 10) : 0));
        return;
    }

    char* ws = (char*)d_ws;
    int*    counts = (int*)ws;
    int*    flag   = (int*)(ws + 256);
    double* sums   = (double*)(ws + sums_off);
    double* h_ws   = (double*)(ws + hws_off);
    double* ag_ws  = (double*)(ws + agws_off);

    int nn = (int)n, CC = (int)C;
    int nb = (nn + 255) / 256;

    hipMemsetAsync(ws, 0, hws_off, stream);   // zero counts + flag + sums

    detect_kernel<<<nb, 256, 0, stream>>>(cid, flag, nn);
    count_kernel<<<nb, 256, 0, stream>>>(cid, flag, counts, nn, CC);
    row_mlp<<<nn, 256, 0, stream>>>(x, cid, flag, W1, b1, W2, b2, sums, nn, CC);
    tail1_kernel<<<CC * 4, 128, 0, stream>>>(counts, sums, fcW, fcb, h_ws);
    tail2a_kernel<<<CC * 2, 128, 0, stream>>>(h_ws, aW, ab, gW, gb, ag_ws);
    tail2b_kernel<<<1, 256, 0, stream>>>(h_ws, ag_ws, cW, cb, rhoW, rhob,
                                         clsW, clsb, counts, sums, cid,
                                         nn, CC, out);
}

// Round 7
// 2508.804 us; speedup vs baseline: 4.8534x; 4.8534x over previous
//
#include <hip/hip_runtime.h>
#include <hip/hip_fp16.h>
#include <math.h>

#define FIN 1024
#define H 512
#define DD 256
#define NCLS 4
#define MAXC 64

#define TM 32     // rows per tile
#define NTB 128   // output-column chunk
#define KT 32     // k tile

// ws layout (bytes), runtime C:
//   counts int[MAXC]   @ 0
//   flag   int         @ 256
//   cursor int[MAXC]   @ 512
//   offs   int[MAXC+1] @ 768
//   sums   double[C*H] @ 1088
//   h_ws   double[C*H] @ 1088 + C*4096
//   ag_ws  double[C*D] @ 1088 + 2*C*4096
//   lists  int[n]      @ 1088 + C*10240
#define WS_SUMS 1088

// ---------------- dtype detect: int32 vs int64 cluster_id ----------------
__global__ void detect_kernel(const int* __restrict__ cid32, int* flag, int n) {
    int i = blockIdx.x * blockDim.x + threadIdx.x;
    if (i < n && (i & 1) && cid32[i] != 0) atomicOr(flag, 1);
}

__device__ __forceinline__ int get_cid(const int* cid, int flag, int i) {
    return flag ? cid[i] : cid[2 * i];   // int32, or low word of int64
}

__global__ void count_kernel(const int* __restrict__ cid, const int* __restrict__ flag,
                             int* counts, int n, int C) {
    int i = blockIdx.x * blockDim.x + threadIdx.x;
    if (i < n) {
        int c = get_cid(cid, *flag, i);
        if ((unsigned)c < (unsigned)C) atomicAdd(&counts[c], 1);
    }
}

__global__ void offsets_kernel(const int* __restrict__ counts, int* offs, int C) {
    if (threadIdx.x == 0 && blockIdx.x == 0) {
        int s = 0;
        offs[0] = 0;
        for (int c = 0; c < C; c++) { s += counts[c]; offs[c + 1] = s; }
    }
}

__global__ void compact_kernel(const int* __restrict__ cid, const int* __restrict__ flag,
                               const int* __restrict__ offs, int* cursor,
                               int* lists, int n, int C) {
    int i = blockIdx.x * blockDim.x + threadIdx.x;
    if (i < n) {
        int c = get_cid(cid, *flag, i);
        if ((unsigned)c < (unsigned)C) {
            int slot = atomicAdd(&cursor[c], 1);
            lists[offs[c] + slot] = i;
        }
    }
}

// ---------------- tiled 2-layer MLP: 32 rows/block, W read once/block ------
// LDS: 4 + 16 + 32 + 4 KB + 128 B = 56.4 KB static (< 64 KB limit)
struct TileSmem {
    float  sX[TM][KT];       // 4 KB
    float  sW[KT][NTB];      // 16 KB
    __half sH[TM][H];        // 32 KB
    float  sPart[8][NTB];    // 4 KB
    int    sIdx[TM];
};

__global__ __launch_bounds__(256) void mlp_tile(
    const float* __restrict__ x, const int* __restrict__ counts,
    const int* __restrict__ offs, const int* __restrict__ lists,
    const float* __restrict__ W1, const float* __restrict__ b1,
    const float* __restrict__ W2, const float* __restrict__ b2,
    double* __restrict__ sums, int maxtiles, int C)
{
    int c = blockIdx.x / maxtiles;
    int t = blockIdx.x % maxtiles;
    int cnt = counts[c];
    int row0 = t * TM;
    if (row0 >= cnt) return;

    __shared__ TileSmem sm;
    int tid = threadIdx.x;
    if (tid < TM) {
        int r = row0 + tid;
        sm.sIdx[tid] = (r < cnt) ? lists[offs[c] + r] : -1;
    }
    __syncthreads();

    const float* W1c = W1 + (size_t)c * FIN * H;
    const float* b1c = b1 + (size_t)c * H;
    const float* W2c = W2 + (size_t)c * H * H;
    const float* b2c = b2 + (size_t)c * H;

    int tc = tid & 31;   // column lane (0..31)
    int tr = tid >> 5;   // row group (0..7): rows tr*4..tr*4+3

    // ================= layer 1: h1 = relu(X @ W1c + b1c) =================
    for (int nb = 0; nb < H; nb += NTB) {
        float acc[4][4];
#pragma unroll
        for (int i = 0; i < 4; i++)
#pragma unroll
            for (int j = 0; j < 4; j++) acc[i][j] = 0.f;

        for (int kk = 0; kk < FIN; kk += KT) {
            __syncthreads();   // prev compute done before restaging sX/sW
            {   // stage X tile: 32x32 floats = 256 threads * float4
                int e = tid * 4;
                int r = e >> 5, k = e & 31;
                int gi = sm.sIdx[r];
                float4 v = make_float4(0.f, 0.f, 0.f, 0.f);
                if (gi >= 0) v = *(const float4*)(x + (size_t)gi * FIN + kk + k);
                *(float4*)&sm.sX[r][k] = v;
            }
#pragma unroll
            for (int it = 0; it < 4; it++) {   // stage W1 tile: 32x128
                int e = it * 1024 + tid * 4;
                int k = e >> 7, j = e & 127;
                *(float4*)&sm.sW[k][j] =
                    *(const float4*)(W1c + (size_t)(kk + k) * H + nb + j);
            }
            __syncthreads();
#pragma unroll
            for (int k4 = 0; k4 < KT; k4 += 4) {
                float xv[4][4];
#pragma unroll
                for (int i = 0; i < 4; i++) {
                    float4 v = *(const float4*)&sm.sX[tr * 4 + i][k4];
                    xv[i][0] = v.x; xv[i][1] = v.y; xv[i][2] = v.z; xv[i][3] = v.w;
                }
#pragma unroll
                for (int kq = 0; kq < 4; kq++) {
                    float wv[4];
#pragma unroll
                    for (int j = 0; j < 4; j++) wv[j] = sm.sW[k4 + kq][tc + 32 * j];
#pragma unroll
                    for (int i = 0; i < 4; i++)
#pragma unroll
                        for (int j = 0; j < 4; j++) acc[i][j] += xv[i][kq] * wv[j];
                }
            }
        }
#pragma unroll
        for (int j = 0; j < 4; j++) {
            int col = nb + tc + 32 * j;
            float bv = b1c[col];
#pragma unroll
            for (int i = 0; i < 4; i++) {
                float v = acc[i][j] + bv;
                sm.sH[tr * 4 + i][col] = __float2half(v > 0.f ? v : 0.f);
            }
        }
    }

    // ============ layer 2: y = relu(h1 @ W2c + b2c); masked column-sum ====
    for (int nb = 0; nb < H; nb += NTB) {
        float acc[4][4];
#pragma unroll
        for (int i = 0; i < 4; i++)
#pragma unroll
            for (int j = 0; j < 4; j++) acc[i][j] = 0.f;

        for (int kk = 0; kk < H; kk += KT) {
            __syncthreads();   // sH epilogue writes / prev sW readers done
#pragma unroll
            for (int it = 0; it < 4; it++) {
                int e = it * 1024 + tid * 4;
                int k = e >> 7, j = e & 127;
                *(float4*)&sm.sW[k][j] =
                    *(const float4*)(W2c + (size_t)(kk + k) * H + nb + j);
            }
            __syncthreads();
#pragma unroll
            for (int k4 = 0; k4 < KT; k4 += 4) {
                float xv[4][4];
#pragma unroll
                for (int i = 0; i < 4; i++) {
                    __half2 p0 = *(const __half2*)&sm.sH[tr * 4 + i][kk + k4];
                    __half2 p1 = *(const __half2*)&sm.sH[tr * 4 + i][kk + k4 + 2];
                    float2 f0 = __half22float2(p0), f1 = __half22float2(p1);
                    xv[i][0] = f0.x; xv[i][1] = f0.y; xv[i][2] = f1.x; xv[i][3] = f1.y;
                }
#pragma unroll
                for (int kq = 0; kq < 4; kq++) {
                    float wv[4];
#pragma unroll
                    for (int j = 0; j < 4; j++) wv[j] = sm.sW[k4 + kq][tc + 32 * j];
#pragma unroll
                    for (int i = 0; i < 4; i++)
#pragma unroll
                        for (int j = 0; j < 4; j++) acc[i][j] += xv[i][kq] * wv[j];
                }
            }
        }
        float psum[4] = {0.f, 0.f, 0.f, 0.f};
#pragma unroll
        for (int i = 0; i < 4; i++) {
            bool valid = sm.sIdx[tr * 4 + i] >= 0;
#pragma unroll
            for (int j = 0; j < 4; j++) {
                float y = acc[i][j] + b2c[nb + tc + 32 * j];
                y = y > 0.f ? y : 0.f;
                if (valid) psum[j] += y;
            }
        }
        __syncthreads();
#pragma unroll
        for (int j = 0; j < 4; j++) sm.sPart[tr][tc + 32 * j] = psum[j];
        __syncthreads();
        if (tid < NTB) {
            float s = 0.f;
#pragma unroll
            for (int r = 0; r < 8; r++) s += sm.sPart[r][tid];
            atomicAdd(&sums[(size_t)c * H + nb + tid], (double)s);
        }
    }
}

// ------------- fallback: one block per row (proven path, ws-lean) ----------
__global__ __launch_bounds__(256) void row_mlp(
    const float* __restrict__ x, const int* __restrict__ cid,
    const int* __restrict__ flag,
    const float* __restrict__ W1, const float* __restrict__ b1,
    const float* __restrict__ W2, const float* __restrict__ b2,
    double* __restrict__ sums, int n, int C)
{
    int r = blockIdx.x;
    if (r >= n) return;
    int c = get_cid(cid, *flag, r);
    if ((unsigned)c >= (unsigned)C) return;

    __shared__ float sx[FIN];
    __shared__ float sh[H];
    int tid = threadIdx.x;

    for (int i = tid; i < FIN; i += 256) sx[i] = x[(size_t)r * FIN + i];
    __syncthreads();

    const float* W1c = W1 + (size_t)c * FIN * H;
    const float* b1c = b1 + (size_t)c * H;
    for (int col = tid; col < H; col += 256) {
        float acc = 0.f;
        for (int k = 0; k < FIN; k++) acc += sx[k] * W1c[(size_t)k * H + col];
        acc += b1c[col];
        sh[col] = acc > 0.f ? acc : 0.f;
    }
    __syncthreads();

    const float* W2c = W2 + (size_t)c * H * H;
    const float* b2c = b2 + (size_t)c * H;
    for (int col = tid; col < H; col += 256) {
        float acc = 0.f;
        for (int k = 0; k < H; k++) acc += sh[k] * W2c[(size_t)k * H + col];
        acc += b2c[col];
        float y = acc > 0.f ? acc : 0.f;
        atomicAdd(&sums[(size_t)c * H + col], (double)y);
    }
}

// -------- tail1: h = relu(mean @ fcW + fcb), per (c, 128-col chunk) --------
__global__ __launch_bounds__(128) void tail1_kernel(
    const int* __restrict__ counts, const double* __restrict__ sums,
    const float* __restrict__ fcW, const float* __restrict__ fcb,
    double* __restrict__ h_ws)
{
    int b = blockIdx.x;
    int c = b >> 2, ch = b & 3;
    int tid = threadIdx.x;
    __shared__ double shc[H];
    double denom = fmax((double)counts[c], 1.0);
    for (int i = tid; i < H; i += 128) shc[i] = sums[(size_t)c * H + i] / denom;
    __syncthreads();
    int col = ch * 128 + tid;
    double acc = (double)fcb[col];
    for (int k = 0; k < H; k++) acc += shc[k] * (double)fcW[k * H + col];
    h_ws[(size_t)c * H + col] = acc > 0.0 ? acc : 0.0;
}

// -------- tail2a: ag = tanh(h@aW+ab) * sigmoid(h@gW+gb) --------
__global__ __launch_bounds__(128) void tail2a_kernel(
    const double* __restrict__ h_ws,
    const float* __restrict__ aW, const float* __restrict__ ab,
    const float* __restrict__ gW, const float* __restrict__ gb,
    double* __restrict__ ag_ws)
{
    int b = blockIdx.x;
    int c = b >> 1, dh = b & 1;
    int tid = threadIdx.x;
    __shared__ double sh[H];
    for (int i = tid; i < H; i += 128) sh[i] = h_ws[(size_t)c * H + i];
    __syncthreads();
    int d = dh * 128 + tid;
    double aa = (double)ab[d], gg = (double)gb[d];
    for (int k = 0; k < H; k++) {
        double hv = sh[k];
        aa += hv * (double)aW[k * DD + d];
        gg += hv * (double)gW[k * DD + d];
    }
    ag_ws[(size_t)c * DD + d] = tanh(aa) / (1.0 + exp(-gg));
}

// -------- tail2b: attention + rho + cls + outputs + diagnostics ------------
__global__ __launch_bounds__(256) void tail2b_kernel(
    const double* __restrict__ h_ws, const double* __restrict__ ag_ws,
    const float* __restrict__ cW, const float* __restrict__ cb,
    const float* __restrict__ rhoW, const float* __restrict__ rhob,
    const float* __restrict__ clsW, const float* __restrict__ clsb,
    const int* __restrict__ counts, const double* __restrict__ sums,
    const int* __restrict__ cid_raw, int n, int C,
    float* __restrict__ out)
{
    int tid = threadIdx.x;
    __shared__ double sA[MAXC];
    __shared__ double shp[H];
    __shared__ double sr[DD];

    if (tid < C) {
        double acc = (double)cb[0];
        for (int d = 0; d < DD; d++)
            acc += ag_ws[(size_t)tid * DD + d] * (double)cW[d];
        sA[tid] = acc;
    }
    __syncthreads();
    if (tid == 0) {
        double m = sA[0];
        for (int c = 1; c < C; c++) m = fmax(m, sA[c]);
        double s = 0.0;
        for (int c = 0; c < C; c++) { sA[c] = exp(sA[c] - m); s += sA[c]; }
        for (int c = 0; c < C; c++) sA[c] /= s;
    }
    __syncthreads();
    for (int col = tid; col < H; col += 256) {
        double s = 0.0;
        for (int c = 0; c < C; c++) s += sA[c] * h_ws[(size_t)c * H + col];
        shp[col] = s;
    }
    __syncthreads();
    for (int d = tid; d < DD; d += 256) {
        double acc = (double)rhob[d];
        for (int k = 0; k < H; k++) acc += shp[k] * (double)rhoW[k * DD + d];
        sr[d] = acc > 0.0 ? acc : 0.0;
    }
    __syncthreads();
    if (tid == 0) {
        double lg[NCLS];
        for (int kk = 0; kk < NCLS; kk++) {
            double acc = (double)clsb[kk];
            for (int d = 0; d < DD; d++) acc += sr[d] * (double)clsW[d * NCLS + kk];
            lg[kk] = acc;
        }
        int am = 0;
        double best = lg[0];
        double run = 1.0;
        for (int kk = 0; kk < NCLS; kk++) {
            if (lg[kk] > best) { best = lg[kk]; am = kk; }
            double hz = 1.0 / (1.0 + exp(-lg[kk]));
            out[kk] = (float)hz;
            run *= (1.0 - hz);
            out[NCLS + kk] = (float)run;
        }
        // ---- stage diagnostics (fire only in failure regimes) ----
        long long cnt_total = 0;
        for (int c = 0; c < C; c++) cnt_total += counts[c];
        double maxs = 0.0;
        for (int i = 0; i < C * H; i++) maxs = fmax(maxs, fabs(sums[i]));
        float yout;
        if (cnt_total == 0) {
            yout = 4.0e6f + (float)((cid_raw[0] & 0xFFF) + 4096 * (cid_raw[1] & 0xFFF));
        } else if (cnt_total != (long long)n) {
            yout = 2.0e6f + (float)cnt_total;
        } else if (maxs == 0.0) {
            yout = 3.0e6f;
        } else {
            yout = (float)am;
        }
        out[2 * NCLS] = yout;
    }
}

__global__ void diag_kernel(float* __restrict__ out, float code) {
    if (threadIdx.x == 0) {
        double run = 1.0;
        for (int kk = 0; kk < NCLS; kk++) {
            out[kk] = 0.5f;
            run *= 0.5;
            out[NCLS + kk] = (float)run;
        }
        out[2 * NCLS] = code;
    }
}

extern "C" void kernel_launch(void* const* d_in, const int* in_sizes, int n_in,
                              void* d_out, int out_size, void* d_ws, size_t ws_size,
                              hipStream_t stream) {
    const float* x    = (const float*)d_in[0];
    const int*   cid  = (const int*)d_in[1];
    const float* W1   = (const float*)d_in[2];
    const float* b1   = (const float*)d_in[3];
    const float* W2   = (const float*)d_in[4];
    const float* b2   = (const float*)d_in[5];
    const float* fcW  = (const float*)d_in[6];
    const float* fcb  = (const float*)d_in[7];
    const float* aW   = (const float*)d_in[8];
    const float* ab   = (const float*)d_in[9];
    const float* gW   = (const float*)d_in[10];
    const float* gb   = (const float*)d_in[11];
    const float* cW   = (const float*)d_in[12];
    const float* cb   = (const float*)d_in[13];
    const float* rhoW = (const float*)d_in[14];
    const float* rhob = (const float*)d_in[15];
    const float* clsW = (const float*)d_in[16];
    const float* clsb = (const float*)d_in[17];
    float* out = (float*)d_out;

    // ---- all shapes derived from in_sizes ----
    long long n = in_sizes[1];
    long long C = (in_sizes[7] > 0) ? (long long)in_sizes[3] / in_sizes[7] : 0;
    bool shapes_ok =
        n > 0 &&
        (long long)in_sizes[0] == n * FIN &&
        in_sizes[7] == H && in_sizes[9] == DD && in_sizes[17] == NCLS &&
        C >= 1 && C <= MAXC &&
        (long long)in_sizes[2] == C * FIN * H &&
        (long long)in_sizes[4] == C * H * H;

    size_t hws_off   = WS_SUMS + (size_t)C * H * 8;
    size_t agws_off  = hws_off + (size_t)C * H * 8;
    size_t lists_off = agws_off + (size_t)C * DD * 8;
    size_t ws_tile   = lists_off + (size_t)n * 4;
    size_t ws_row    = lists_off;            // fallback needs no lists

    if (!shapes_ok) {
        diag_kernel<<<1, 64, 0, stream>>>(out, 7.0e6f + (float)(C >= 0 ? C : 0));
        return;
    }
    if (ws_size < ws_row) {
        diag_kernel<<<1, 64, 0, stream>>>(
            out, 6.0e6f + (float)(ws_size > 0 ? (ws_size >> 10) : 0));
        return;
    }

    char* ws = (char*)d_ws;
    int*    counts = (int*)ws;
    int*    flag   = (int*)(ws + 256);
    int*    cursor = (int*)(ws + 512);
    int*    offs   = (int*)(ws + 768);
    double* sums   = (double*)(ws + WS_SUMS);
    double* h_ws   = (double*)(ws + hws_off);
    double* ag_ws  = (double*)(ws + agws_off);
    int*    lists  = (int*)(ws + lists_off);

    int nn = (int)n, CC = (int)C;
    int nb = (nn + 255) / 256;

    hipMemsetAsync(ws, 0, hws_off, stream);  // counts+flag+cursor+offs+sums

    detect_kernel<<<nb, 256, 0, stream>>>(cid, flag, nn);
    count_kernel<<<nb, 256, 0, stream>>>(cid, flag, counts, nn, CC);

    if (ws_size >= ws_tile) {
        offsets_kernel<<<1, 64, 0, stream>>>(counts, offs, CC);
        compact_kernel<<<nb, 256, 0, stream>>>(cid, flag, offs, cursor, lists, nn, CC);
        int maxtiles = (nn + TM - 1) / TM;
        mlp_tile<<<CC * maxtiles, 256, 0, stream>>>(x, counts, offs, lists,
                                                    W1, b1, W2, b2, sums,
                                                    maxtiles, CC);
    } else {
        row_mlp<<<nn, 256, 0, stream>>>(x, cid, flag, W1, b1, W2, b2, sums, nn, CC);
    }

    tail1_kernel<<<CC * 4, 128, 0, stream>>>(counts, sums, fcW, fcb, h_ws);
    tail2a_kernel<<<CC * 2, 128, 0, stream>>>(h_ws, aW, ab, gW, gb, ag_ws);
    tail2b_kernel<<<1, 256, 0, stream>>>(h_ws, ag_ws, cW, cb, rhoW, rhob,
                                         clsW, clsb, counts, sums, cid,
                                         nn, CC, out);
}